// Round 6
// baseline (277.907 us; speedup 1.0000x reference)
//
#include <hip/hip_runtime.h>

#define BB  8
#define CC  64
#define HH  128
#define WW  128
#define OCC 18   // 2*KK offset channels
#define XP  133  // padded spatial dim (pad 2 low, 3 high; offsets clipped to +-1)
#define SP  72   // LDS sample pitch in shorts (16B-aligned rows)
#define XTP 68   // xt transpose-LDS pitch

typedef __attribute__((ext_vector_type(8)))  short bf16x8;
typedef __attribute__((ext_vector_type(16))) float f32x16;

static __device__ __forceinline__ ushort f2bf(float f) {
    union { float f; unsigned u; } v; v.f = f;
    unsigned r = (v.u + 0x7FFFu + ((v.u >> 16) & 1u)) >> 16;  // RNE
    return (ushort)r;
}
static __device__ __forceinline__ float bfu(unsigned u) {
    union { unsigned u; float f; } v; v.u = u; return v.f;
}

// ---------------------------------------------------------------------------
// WA[t 25][oc 32][c 64] bf16 from ow (18,64,5,5); oc>=18 zero-padded
// ---------------------------------------------------------------------------
__global__ __launch_bounds__(256) void wa_kernel(
    const float* __restrict__ ow, ushort* __restrict__ WA)
{
    int idx = blockIdx.x * 256 + threadIdx.x;   // 25*32*64 = 51200
    if (idx >= 25 * 32 * 64) return;
    int t  = idx >> 11;
    int oc = (idx >> 6) & 31;
    int c  = idx & 63;
    float v = (oc < OCC) ? ow[((size_t)(oc * CC + c)) * 25 + t] : 0.f;
    WA[idx] = f2bf(v);
}

// ---------------------------------------------------------------------------
// WD[t 9][o 64][c 64] bf16 from w (64,64,3,3)
// ---------------------------------------------------------------------------
__global__ __launch_bounds__(256) void wd_kernel(
    const float* __restrict__ w, ushort* __restrict__ WD)
{
    int idx = blockIdx.x * 256 + threadIdx.x;   // 9*64*64 = 36864
    if (idx >= 9 * 64 * 64) return;
    int t = idx >> 12;
    int o = (idx >> 6) & 63;
    int c = idx & 63;
    WD[idx] = f2bf(w[((size_t)(o * CC + c)) * 9 + t]);
}

// ---------------------------------------------------------------------------
// XT[b][y' XP][x' XP][c 64] bf16, zero-padded. Half-row blocks (grid 2048)
// + 40 border-zero blocks.
// ---------------------------------------------------------------------------
__global__ __launch_bounds__(256) void xt_kernel(
    const float* __restrict__ x, ushort* __restrict__ XT)
{
    __shared__ ushort T[64 * XTP];   // 8704 B
    const int tid = threadIdx.x;

    if (blockIdx.x >= 2 * BB * HH) {              // y-border zero rows
        int idx = blockIdx.x - 2 * BB * HH;       // 0..39
        int b = idx / 5;
        int r = idx % 5;
        int yp = (r < 2) ? r : (128 + r);         // {0,1,130,131,132}
        uint4* row = (uint4*)(XT + ((size_t)b * XP + yp) * XP * 64);
        for (int i = tid; i < XP * 8; i += 256) row[i] = make_uint4(0, 0, 0, 0);
        return;
    }

    const int half = blockIdx.x & 1;
    const int y    = (blockIdx.x >> 1) & 127;
    const int b    = blockIdx.x >> 8;
    const int p    = tid & 63;
    const int ch4  = tid >> 6;

    const float* xb = x + (size_t)b * CC * HH * WW + (size_t)y * WW + half * 64;
#pragma unroll
    for (int i = 0; i < 16; i++) {
        int c = i * 4 + ch4;
        T[p * XTP + c] = f2bf(xb[(size_t)c * HH * WW + p]);
    }
    __syncthreads();

    ushort* orow = XT + (((size_t)b * XP + (y + 2)) * XP) * 64;

    if (half == 0) {                              // x' in {0,1}: zeros
        if (tid < 16) {
            int col = tid >> 3;
            ((uint4*)(orow + (size_t)col * 64))[tid & 7] = make_uint4(0, 0, 0, 0);
        }
    } else {                                      // x' in {130,131,132}: zeros
        if (tid < 24) {
            int col = 130 + (tid >> 3);
            ((uint4*)(orow + (size_t)col * 64))[tid & 7] = make_uint4(0, 0, 0, 0);
        }
    }

#pragma unroll
    for (int g = 0; g < 2; g++) {                 // interior: x' = half*64+pl+2
        int idx = g * 256 + tid;                  // 512 chunks of 8 shorts
        int pl = idx >> 3;
        int part = idx & 7;
        uint2 lo = *(const uint2*)&T[pl * XTP + part * 8];
        uint2 hi = *(const uint2*)&T[pl * XTP + part * 8 + 4];
        uint4 wv; wv.x = lo.x; wv.y = lo.y; wv.z = hi.x; wv.w = hi.y;
        ((uint4*)(orow + ((size_t)(half * 64 + pl + 2)) * 64))[part] = wv;
    }
}

// ---------------------------------------------------------------------------
// FUSED kernel. Block = (b, y, px-half 64). Grid 2048, 4 waves.
// Phase A: offset conv via MFMA, taps split across wave-pairs, LDS-reduced,
//          bias+clip -> off_lds[18][64] (never hits global).
// Phase B: per tap gather bilinear bf16 samples from XT -> S[64px][64c] LDS,
//          GEMM out[64o][64px] += WD[t] x S. Wave tiles 32x32.
// ---------------------------------------------------------------------------
__global__ __launch_bounds__(256, 6) void fused_kernel(
    const ushort* __restrict__ XT, const ushort* __restrict__ WA,
    const ushort* __restrict__ WD, const float* __restrict__ ob,
    float* __restrict__ out)
{
    __shared__ char smem[64 * SP * 2];            // 9216 B: S (phase B) / red (phase A)
    __shared__ float off_lds[OCC * 64];           // 4608 B
    ushort* S   = (ushort*)smem;
    float*  red = (float*)smem;                   // 2*16*64 f32 = 8192 B

    const int tid   = threadIdx.x;
    const int lane  = tid & 63;
    const int n     = lane & 31;
    const int h     = lane >> 5;
    const int w     = tid >> 6;
    const int ptile = w & 1;          // 32-wide px/o tile select
    const int tset  = w >> 1;         // tap-half (A) / px-tile (B)
    const int half  = blockIdx.x & 1;
    const int y     = (blockIdx.x >> 1) & 127;
    const int b     = blockIdx.x >> 8;

    // ================= Phase A: offset conv row-half ======================
    {
        f32x16 acc = {};
        const ushort* rb0 = XT + (((size_t)b * XP + y) * XP + half * 64 + ptile * 32 + n) * 64 + h * 8;
        const ushort* ap  = WA + ((size_t)n) * 64 + h * 8;
        const int t0 = tset ? 13 : 0;
        const int t1 = tset ? 25 : 13;
        for (int t = t0; t < t1; t++) {
            const int ky = t / 5, kx = t % 5;
            const ushort* bp = rb0 + ((size_t)ky * XP + kx) * 64;
            const ushort* at = ap + (size_t)t * 2048;
#pragma unroll
            for (int cs = 0; cs < 4; cs++) {
                bf16x8 af = *(const bf16x8*)(at + cs * 16);
                bf16x8 bf = *(const bf16x8*)(bp + cs * 16);
                acc = __builtin_amdgcn_mfma_f32_32x32x16_bf16(af, bf, acc, 0, 0, 0);
            }
        }
        if (tset == 1) {
#pragma unroll
            for (int r = 0; r < 16; r++)
                red[ptile * 1024 + r * 64 + lane] = acc[r];
        }
        __syncthreads();
        if (tset == 0) {
#pragma unroll
            for (int r = 0; r < 16; r++) {
                int oc = (r & 3) + 8 * (r >> 2) + 4 * h;
                if (oc < OCC) {
                    float v = acc[r] + red[ptile * 1024 + r * 64 + lane] + ob[oc];
                    v = fminf(fmaxf(v, -1.f), 1.f);
                    off_lds[oc * 64 + ptile * 32 + n] = v;
                }
            }
        }
        __syncthreads();   // off_lds ready; red reads done (S reuse safe)
    }

    // ================= Phase B: deform sample + einsum ====================
    const int p    = tid & 63;            // gather pixel (local)
    const int csec = (tid >> 6) * 16;     // gather channel section

    const int m0 = ptile * 32;            // o tile
    const int n0 = tset * 32;             // px tile

    f32x16 acc = {};
    const ushort* xtb = XT + (size_t)b * XP * XP * 64;

    for (int t = 0; t < 9; t++) {
        float dy = off_lds[(2 * t) * 64 + p];
        float dx = off_lds[(2 * t + 1) * 64 + p];
        float py = (float)(y + t / 3 - 1) + dy;
        float px = (float)(half * 64 + p + t % 3 - 1) + dx;
        float y0f = floorf(py), x0f = floorf(px);
        float fy = py - y0f, fx = px - x0f;
        int iy = (int)y0f + 2, ix = (int)x0f + 2;
        float w00 = (1.f - fy) * (1.f - fx), w01 = (1.f - fy) * fx;
        float w10 = fy * (1.f - fx),         w11 = fy * fx;

        const ushort* c00 = xtb + ((size_t)iy * XP + ix) * 64 + csec;
        const ushort* c10 = c00 + XP * 64;

        uint4 q[8];
        q[0] = *(const uint4*)(c00);      q[1] = *(const uint4*)(c00 + 8);
        q[2] = *(const uint4*)(c00 + 64); q[3] = *(const uint4*)(c00 + 72);
        q[4] = *(const uint4*)(c10);      q[5] = *(const uint4*)(c10 + 8);
        q[6] = *(const uint4*)(c10 + 64); q[7] = *(const uint4*)(c10 + 72);

        if (t) __syncthreads();   // all waves done reading S[t-1]

#pragma unroll
        for (int m = 0; m < 2; m++) {
            unsigned o4[4];
#pragma unroll
            for (int j = 0; j < 4; j++) {
                unsigned u00 = ((const unsigned*)&q[m])[j];
                unsigned u01 = ((const unsigned*)&q[2 + m])[j];
                unsigned u10 = ((const unsigned*)&q[4 + m])[j];
                unsigned u11 = ((const unsigned*)&q[6 + m])[j];
                float lo = w00 * bfu(u00 << 16) + w01 * bfu(u01 << 16)
                         + w10 * bfu(u10 << 16) + w11 * bfu(u11 << 16);
                float hi = w00 * bfu(u00 & 0xffff0000u) + w01 * bfu(u01 & 0xffff0000u)
                         + w10 * bfu(u10 & 0xffff0000u) + w11 * bfu(u11 & 0xffff0000u);
                o4[j] = (unsigned)f2bf(lo) | ((unsigned)f2bf(hi) << 16);
            }
            *(uint4*)&S[p * SP + csec + m * 8] = *(uint4*)o4;
        }
        __syncthreads();

        const ushort* at = WD + ((size_t)(t * 64 + m0 + n)) * 64 + h * 8;
        const ushort* bp = &S[(n0 + n) * SP + h * 8];
#pragma unroll
        for (int cs = 0; cs < 4; cs++) {
            bf16x8 af = *(const bf16x8*)(at + cs * 16);
            bf16x8 bf = *(const bf16x8*)(bp + cs * 16);
            acc = __builtin_amdgcn_mfma_f32_32x32x16_bf16(af, bf, acc, 0, 0, 0);
        }
    }

    // epilogue: C/D col=lane&31 (px), row=(r&3)+8*(r>>2)+4*h (o)
#pragma unroll
    for (int r = 0; r < 16; r++) {
        int o = m0 + (r & 3) + 8 * (r >> 2) + 4 * h;
        out[((size_t)(b * CC + o) * HH + y) * WW + half * 64 + n0 + n] = acc[r];
    }
}

// ---------------------------------------------------------------------------
extern "C" void kernel_launch(void* const* d_in, const int* in_sizes, int n_in,
                              void* d_out, int out_size, void* d_ws, size_t ws_size,
                              hipStream_t stream)
{
    const float* x  = (const float*)d_in[0];   // (8,64,128,128)
    const float* w  = (const float*)d_in[1];   // (64,64,3,3)
    const float* ow = (const float*)d_in[2];   // (18,64,5,5)
    const float* ob = (const float*)d_in[3];   // (18,)
    float* out = (float*)d_out;                // (8,64,128,128)

    // workspace: XT 18,113,536 | WA 102,400 | WD 73,728
    ushort* XT = (ushort*)d_ws;
    ushort* WA = (ushort*)((char*)d_ws + 18113536);
    ushort* WD = (ushort*)((char*)d_ws + 18215936);

    wa_kernel<<<200, 256, 0, stream>>>(ow, WA);
    wd_kernel<<<144, 256, 0, stream>>>(w, WD);
    xt_kernel<<<2 * BB * HH + 40, 256, 0, stream>>>(x, XT);
    fused_kernel<<<2 * BB * HH, 256, 0, stream>>>(XT, WA, WD, ob, out);
}

// Round 7
// 162.209 us; speedup vs baseline: 1.7133x; 1.7133x over previous
//
#include <hip/hip_runtime.h>

#define BB  8
#define CC  64
#define HH  128
#define WW  128
#define OCC 18   // 2*KK offset channels
#define XP  133  // padded spatial dim (pad 2 low, 3 high; offsets clipped to +-1)
#define SP  72   // LDS pitch in shorts (144B: 16B-aligned, measured 0 conflicts)
#define XTP 68   // xt transpose-LDS pitch

typedef __attribute__((ext_vector_type(8)))  short bf16x8;
typedef __attribute__((ext_vector_type(16))) float f32x16;

static __device__ __forceinline__ ushort f2bf(float f) {
    union { float f; unsigned u; } v; v.f = f;
    unsigned r = (v.u + 0x7FFFu + ((v.u >> 16) & 1u)) >> 16;  // RNE
    return (ushort)r;
}
static __device__ __forceinline__ float bfu(unsigned u) {
    union { unsigned u; float f; } v; v.u = u; return v.f;
}

// ---------------------------------------------------------------------------
// WAf: offset-conv A-operand in MFMA-fragment order: [t 25][cs 4][lane 64][8]
// lane l holds oc=l&31, ch = cs*16 + (l>>5)*8 + j  ->  1KB contiguous per frag
// ---------------------------------------------------------------------------
__global__ __launch_bounds__(256) void waf_kernel(
    const float* __restrict__ ow, ushort* __restrict__ WAf)
{
    int idx = blockIdx.x * 256 + threadIdx.x;   // 25*4*64*8 = 51200
    if (idx >= 25 * 4 * 64 * 8) return;
    int j  = idx & 7;
    int l  = (idx >> 3) & 63;
    int cs = (idx >> 9) & 3;
    int t  = idx >> 11;
    int oc = l & 31;
    int c  = cs * 16 + (l >> 5) * 8 + j;
    float v = (oc < OCC) ? ow[((size_t)(oc * CC + c)) * 25 + t] : 0.f;
    WAf[idx] = f2bf(v);
}

// ---------------------------------------------------------------------------
// WDf: deform A-operand fragment order: [t 9][mt 2][cs 4][lane 64][8]
// lane l holds o = mt*32 + (l&31), ch = cs*16 + (l>>5)*8 + j
// ---------------------------------------------------------------------------
__global__ __launch_bounds__(256) void wdf_kernel(
    const float* __restrict__ w, ushort* __restrict__ WDf)
{
    int idx = blockIdx.x * 256 + threadIdx.x;   // 9*2*4*64*8 = 36864
    if (idx >= 9 * 2 * 4 * 64 * 8) return;
    int j  = idx & 7;
    int l  = (idx >> 3) & 63;
    int cs = (idx >> 9) & 3;
    int mt = (idx >> 11) & 1;
    int t  = idx >> 12;
    int o  = mt * 32 + (l & 31);
    int c  = cs * 16 + (l >> 5) * 8 + j;
    WDf[idx] = f2bf(w[((size_t)(o * CC + c)) * 9 + t]);
}

// ---------------------------------------------------------------------------
// XT[b][y' XP][x' XP][c 64] bf16, zero-padded. Half-row blocks (grid 2048)
// + 40 border-zero blocks. (unchanged from round 6)
// ---------------------------------------------------------------------------
__global__ __launch_bounds__(256) void xt_kernel(
    const float* __restrict__ x, ushort* __restrict__ XT)
{
    __shared__ ushort T[64 * XTP];
    const int tid = threadIdx.x;

    if (blockIdx.x >= 2 * BB * HH) {              // y-border zero rows
        int idx = blockIdx.x - 2 * BB * HH;       // 0..39
        int b = idx / 5;
        int r = idx % 5;
        int yp = (r < 2) ? r : (128 + r);         // {0,1,130,131,132}
        uint4* row = (uint4*)(XT + ((size_t)b * XP + yp) * XP * 64);
        for (int i = tid; i < XP * 8; i += 256) row[i] = make_uint4(0, 0, 0, 0);
        return;
    }

    const int half = blockIdx.x & 1;
    const int y    = (blockIdx.x >> 1) & 127;
    const int b    = blockIdx.x >> 8;
    const int p    = tid & 63;
    const int ch4  = tid >> 6;

    const float* xb = x + (size_t)b * CC * HH * WW + (size_t)y * WW + half * 64;
#pragma unroll
    for (int i = 0; i < 16; i++) {
        int c = i * 4 + ch4;
        T[p * XTP + c] = f2bf(xb[(size_t)c * HH * WW + p]);
    }
    __syncthreads();

    ushort* orow = XT + (((size_t)b * XP + (y + 2)) * XP) * 64;

    if (half == 0) {
        if (tid < 16) {
            int col = tid >> 3;
            ((uint4*)(orow + (size_t)col * 64))[tid & 7] = make_uint4(0, 0, 0, 0);
        }
    } else {
        if (tid < 24) {
            int col = 130 + (tid >> 3);
            ((uint4*)(orow + (size_t)col * 64))[tid & 7] = make_uint4(0, 0, 0, 0);
        }
    }

#pragma unroll
    for (int g = 0; g < 2; g++) {
        int idx = g * 256 + tid;
        int pl = idx >> 3;
        int part = idx & 7;
        uint2 lo = *(const uint2*)&T[pl * XTP + part * 8];
        uint2 hi = *(const uint2*)&T[pl * XTP + part * 8 + 4];
        uint4 wv; wv.x = lo.x; wv.y = lo.y; wv.z = hi.x; wv.w = hi.y;
        ((uint4*)(orow + ((size_t)(half * 64 + pl + 2)) * 64))[part] = wv;
    }
}

// ---------------------------------------------------------------------------
// FUSED kernel, round 7: all MFMA A-operands are contiguous fragment loads;
// phase A B-operand staged per-ky in LDS (coalesced stream); phase B gather
// permuted so 4 lanes cover one pixel's cacheline.
// ---------------------------------------------------------------------------
__global__ __launch_bounds__(256, 6) void fused_kernel(
    const ushort* __restrict__ XT, const ushort* __restrict__ WAf,
    const ushort* __restrict__ WDf, const float* __restrict__ ob,
    float* __restrict__ out)
{
    __shared__ __align__(16) char smem[68 * SP * 2];   // 9792B: XROW / red / S
    __shared__ float off_lds[OCC * 64];                // 4608B

    const int tid   = threadIdx.x;
    const int lane  = tid & 63;
    const int n     = lane & 31;
    const int h     = lane >> 5;
    const int w     = tid >> 6;
    const int ptile = w & 1;          // 32-wide px tile (A) / o tile (B)
    const int tset  = w >> 1;         // cs-half (A) / px tile (B)
    const int half  = blockIdx.x & 1;
    const int y     = (blockIdx.x >> 1) & 127;
    const int b     = blockIdx.x >> 8;

    // ================= Phase A: offset conv row-half ======================
    {
        ushort* XROW = (ushort*)smem;             // [68 px][SP]
        float*  red  = (float*)smem;
        f32x16 acc = {};
        const ushort* src0 = XT + (((size_t)b * XP + y) * XP + half * 64) * 64;

        for (int ky = 0; ky < 5; ky++) {
            if (ky) __syncthreads();              // prior ds_reads done
            const ushort* src = src0 + (size_t)ky * XP * 64;
            for (int i = tid; i < 68 * 8; i += 256) {
                int pl = i >> 3, ch = (i & 7) * 8;
                *(uint4*)&XROW[pl * SP + ch] = *(const uint4*)(src + (size_t)pl * 64 + ch);
            }
            __syncthreads();

#pragma unroll
            for (int kx = 0; kx < 5; kx++) {
                const int t = ky * 5 + kx;
                const ushort* bbase = &XROW[(ptile * 32 + n + kx) * SP + h * 8];
#pragma unroll
                for (int c2 = 0; c2 < 2; c2++) {
                    const int cs = tset * 2 + c2;
                    bf16x8 af = *(const bf16x8*)(WAf + (((size_t)t * 4 + cs) * 64 + lane) * 8);
                    bf16x8 bf = *(const bf16x8*)(bbase + cs * 16);
                    acc = __builtin_amdgcn_mfma_f32_32x32x16_bf16(af, bf, acc, 0, 0, 0);
                }
            }
        }
        __syncthreads();                          // last ds_reads done; XROW -> red
        if (tset == 1) {
#pragma unroll
            for (int r = 0; r < 16; r++)
                red[ptile * 1024 + r * 64 + lane] = acc[r];
        }
        __syncthreads();
        if (tset == 0) {
#pragma unroll
            for (int r = 0; r < 16; r++) {
                int oc = (r & 3) + 8 * (r >> 2) + 4 * h;
                if (oc < OCC) {
                    float v = acc[r] + red[ptile * 1024 + r * 64 + lane] + ob[oc];
                    v = fminf(fmaxf(v, -1.f), 1.f);
                    off_lds[oc * 64 + ptile * 32 + n] = v;
                }
            }
        }
        __syncthreads();                          // off_lds ready; red reads done
    }

    // ================= Phase B: deform sample + einsum ====================
    ushort* S = (ushort*)smem;                    // [64 px][SP]
    const int p   = tid >> 2;                     // gather pixel (4 lanes/pixel)
    const int cs4 = (tid & 3) * 16;               // channel section (shorts)

    const int m0 = ptile * 32;                    // o tile
    const int n0 = tset * 32;                     // px tile

    f32x16 acc = {};
    const ushort* xtb = XT + (size_t)b * XP * XP * 64;

    for (int t = 0; t < 9; t++) {
        float dy = off_lds[(2 * t) * 64 + p];
        float dx = off_lds[(2 * t + 1) * 64 + p];
        float py = (float)(y + t / 3 - 1) + dy;
        float px = (float)(half * 64 + p + t % 3 - 1) + dx;
        float y0f = floorf(py), x0f = floorf(px);
        float fy = py - y0f, fx = px - x0f;
        int iy = (int)y0f + 2, ix = (int)x0f + 2;
        float w00 = (1.f - fy) * (1.f - fx), w01 = (1.f - fy) * fx;
        float w10 = fy * (1.f - fx),         w11 = fy * fx;

        const ushort* c00 = xtb + ((size_t)iy * XP + ix) * 64 + cs4;
        const ushort* c10 = c00 + XP * 64;

        uint4 q[8];
        q[0] = *(const uint4*)(c00);      q[1] = *(const uint4*)(c00 + 8);
        q[2] = *(const uint4*)(c00 + 64); q[3] = *(const uint4*)(c00 + 72);
        q[4] = *(const uint4*)(c10);      q[5] = *(const uint4*)(c10 + 8);
        q[6] = *(const uint4*)(c10 + 64); q[7] = *(const uint4*)(c10 + 72);

        __syncthreads();   // S (or red at t=0) reads done before overwrite

#pragma unroll
        for (int m = 0; m < 2; m++) {
            unsigned o4[4];
#pragma unroll
            for (int j = 0; j < 4; j++) {
                unsigned u00 = ((const unsigned*)&q[m])[j];
                unsigned u01 = ((const unsigned*)&q[2 + m])[j];
                unsigned u10 = ((const unsigned*)&q[4 + m])[j];
                unsigned u11 = ((const unsigned*)&q[6 + m])[j];
                float lo = w00 * bfu(u00 << 16) + w01 * bfu(u01 << 16)
                         + w10 * bfu(u10 << 16) + w11 * bfu(u11 << 16);
                float hi = w00 * bfu(u00 & 0xffff0000u) + w01 * bfu(u01 & 0xffff0000u)
                         + w10 * bfu(u10 & 0xffff0000u) + w11 * bfu(u11 & 0xffff0000u);
                o4[j] = (unsigned)f2bf(lo) | ((unsigned)f2bf(hi) << 16);
            }
            *(uint4*)&S[p * SP + cs4 + m * 8] = *(uint4*)o4;
        }
        __syncthreads();

        const ushort* bp = &S[(n0 + n) * SP + h * 8];
#pragma unroll
        for (int cs = 0; cs < 4; cs++) {
            bf16x8 af = *(const bf16x8*)(WDf + ((((size_t)t * 2 + ptile) * 4 + cs) * 64 + lane) * 8);
            bf16x8 bf = *(const bf16x8*)(bp + cs * 16);
            acc = __builtin_amdgcn_mfma_f32_32x32x16_bf16(af, bf, acc, 0, 0, 0);
        }
    }

    // epilogue: C/D col=lane&31 (px), row=(r&3)+8*(r>>2)+4*h (o)
#pragma unroll
    for (int r = 0; r < 16; r++) {
        int o = m0 + (r & 3) + 8 * (r >> 2) + 4 * h;
        out[((size_t)(b * CC + o) * HH + y) * WW + half * 64 + n0 + n] = acc[r];
    }
}

// ---------------------------------------------------------------------------
extern "C" void kernel_launch(void* const* d_in, const int* in_sizes, int n_in,
                              void* d_out, int out_size, void* d_ws, size_t ws_size,
                              hipStream_t stream)
{
    const float* x  = (const float*)d_in[0];   // (8,64,128,128)
    const float* w  = (const float*)d_in[1];   // (64,64,3,3)
    const float* ow = (const float*)d_in[2];   // (18,64,5,5)
    const float* ob = (const float*)d_in[3];   // (18,)
    float* out = (float*)d_out;                // (8,64,128,128)

    // workspace: XT 18,113,536 | WAf 102,400 | WDf 73,728
    ushort* XT  = (ushort*)d_ws;
    ushort* WAf = (ushort*)((char*)d_ws + 18113536);
    ushort* WDf = (ushort*)((char*)d_ws + 18215936);

    waf_kernel<<<200, 256, 0, stream>>>(ow, WAf);
    wdf_kernel<<<144, 256, 0, stream>>>(w, WDf);
    xt_kernel<<<2 * BB * HH + 40, 256, 0, stream>>>(x, XT);
    fused_kernel<<<2 * BB * HH, 256, 0, stream>>>(XT, WAf, WDf, ob, out);
}

// Round 8
// 149.842 us; speedup vs baseline: 1.8547x; 1.0825x over previous
//
#include <hip/hip_runtime.h>

#define BB  8
#define CC  64
#define HH  128
#define WW  128
#define OCC 18   // 2*KK offset channels
#define XP  133  // padded spatial dim (pad 2 low, 3 high; offsets clipped to +-1)
#define SP  72   // LDS pitch in shorts (144B: 16B-aligned, measured 0 conflicts)
#define XTP 68   // transpose-LDS pitch

typedef __attribute__((ext_vector_type(8)))  short bf16x8;
typedef __attribute__((ext_vector_type(16))) float f32x16;

static __device__ __forceinline__ ushort f2bf(float f) {
    union { float f; unsigned u; } v; v.f = f;
    unsigned r = (v.u + 0x7FFFu + ((v.u >> 16) & 1u)) >> 16;  // RNE
    return (ushort)r;
}
static __device__ __forceinline__ float bfu(unsigned u) {
    union { unsigned u; float f; } v; v.u = u; return v.f;
}

// ---------------------------------------------------------------------------
// PREP (single launch): blocks 0..2047 build XT with batch-per-XCD placement
// (b = blockIdx&7 so XT[b] is written by—and stays resident in—XCD b's L2);
// blocks 2048..2247 build WAf; 2248..2391 build WDf.
// WAf: [t 25][cs 4][lane 64][8]  lane l: oc=l&31, c=cs*16+(l>>5)*8+j
// WDf: [t 9][mt 2][cs 4][lane 64][8] lane l: o=mt*32+(l&31), same c map
// ---------------------------------------------------------------------------
__global__ __launch_bounds__(256) void prep_kernel(
    const float* __restrict__ x, const float* __restrict__ w,
    const float* __restrict__ ow, ushort* __restrict__ XT,
    ushort* __restrict__ WAf, ushort* __restrict__ WDf)
{
    __shared__ ushort T[64 * XTP];
    const int tid = threadIdx.x;
    const int phys = blockIdx.x;

    if (phys >= 2 * BB * HH) {                    // weight-prep blocks
        int id = phys - 2 * BB * HH;
        if (id < 200) {                           // WAf: 51200 elements
            int idx = id * 256 + tid;
            int j  = idx & 7;
            int l  = (idx >> 3) & 63;
            int cs = (idx >> 9) & 3;
            int t  = idx >> 11;
            int oc = l & 31;
            int c  = cs * 16 + (l >> 5) * 8 + j;
            float v = (oc < OCC) ? ow[((size_t)(oc * CC + c)) * 25 + t] : 0.f;
            WAf[idx] = f2bf(v);
        } else {                                  // WDf: 36864 elements
            int idx = (id - 200) * 256 + tid;
            int j  = idx & 7;
            int l  = (idx >> 3) & 63;
            int cs = (idx >> 9) & 3;
            int mt = (idx >> 11) & 1;
            int t  = idx >> 12;
            int o  = mt * 32 + (l & 31);
            int c  = cs * 16 + (l >> 5) * 8 + j;
            WDf[idx] = f2bf(w[((size_t)(o * CC + c)) * 9 + t]);
        }
        return;
    }

    // ---- XT blocks: batch-per-XCD swizzle
    const int b    = phys & 7;                    // XCD id == batch
    const int idx  = phys >> 3;                   // 0..255 within batch
    const int half = idx & 1;
    const int y    = idx >> 1;

    // y-border zero rows {0,1,130,131,132}: 5*XP*8 uint4s spread over the
    // first 21 blocks of this batch (kept on the owning XCD)
    {
        int j = idx * 256 + tid;
        if (j < 5 * XP * 8) {
            int r   = j / (XP * 8);
            int off = j % (XP * 8);
            int yp  = (r < 2) ? r : (128 + r);
            ((uint4*)(XT + ((size_t)b * XP + yp) * XP * 64))[off] = make_uint4(0, 0, 0, 0);
        }
    }

    const int p   = tid & 63;
    const int ch4 = tid >> 6;
    const float* xb = x + (size_t)b * CC * HH * WW + (size_t)y * WW + half * 64;
#pragma unroll
    for (int i = 0; i < 16; i++) {
        int c = i * 4 + ch4;
        T[p * XTP + c] = f2bf(xb[(size_t)c * HH * WW + p]);
    }
    __syncthreads();

    ushort* orow = XT + (((size_t)b * XP + (y + 2)) * XP) * 64;

    if (half == 0) {                              // x' in {0,1}: zeros
        if (tid < 16) {
            int col = tid >> 3;
            ((uint4*)(orow + (size_t)col * 64))[tid & 7] = make_uint4(0, 0, 0, 0);
        }
    } else {                                      // x' in {130,131,132}: zeros
        if (tid < 24) {
            int col = 130 + (tid >> 3);
            ((uint4*)(orow + (size_t)col * 64))[tid & 7] = make_uint4(0, 0, 0, 0);
        }
    }

#pragma unroll
    for (int g = 0; g < 2; g++) {                 // interior: x' = half*64+pl+2
        int i2 = g * 256 + tid;
        int pl = i2 >> 3;
        int part = i2 & 7;
        uint2 lo = *(const uint2*)&T[pl * XTP + part * 8];
        uint2 hi = *(const uint2*)&T[pl * XTP + part * 8 + 4];
        uint4 wv; wv.x = lo.x; wv.y = lo.y; wv.z = hi.x; wv.w = hi.y;
        ((uint4*)(orow + ((size_t)(half * 64 + pl + 2)) * 64))[part] = wv;
    }
}

// ---------------------------------------------------------------------------
// FUSED kernel (round 8: batch-per-XCD swizzle; body unchanged from r7).
// ---------------------------------------------------------------------------
__global__ __launch_bounds__(256, 6) void fused_kernel(
    const ushort* __restrict__ XT, const ushort* __restrict__ WAf,
    const ushort* __restrict__ WDf, const float* __restrict__ ob,
    float* __restrict__ out)
{
    __shared__ __align__(16) char smem[68 * SP * 2];   // 9792B: XROW / red / S
    __shared__ float off_lds[OCC * 64];                // 4608B

    const int tid   = threadIdx.x;
    const int lane  = tid & 63;
    const int n     = lane & 31;
    const int h     = lane >> 5;
    const int w     = tid >> 6;
    const int ptile = w & 1;          // 32-wide px tile (A) / o tile (B)
    const int tset  = w >> 1;         // cs-half (A) / px tile (B)

    // batch-per-XCD swizzle: same mapping as prep => XT[b] is L2-resident here
    const int b    = blockIdx.x & 7;
    const int idx  = blockIdx.x >> 3;
    const int half = idx & 1;
    const int y    = idx >> 1;

    // ================= Phase A: offset conv row-half ======================
    {
        ushort* XROW = (ushort*)smem;             // [68 px][SP]
        float*  red  = (float*)smem;
        f32x16 acc = {};
        const ushort* src0 = XT + (((size_t)b * XP + y) * XP + half * 64) * 64;

        for (int ky = 0; ky < 5; ky++) {
            if (ky) __syncthreads();              // prior ds_reads done
            const ushort* src = src0 + (size_t)ky * XP * 64;
            for (int i = tid; i < 68 * 8; i += 256) {
                int pl = i >> 3, ch = (i & 7) * 8;
                *(uint4*)&XROW[pl * SP + ch] = *(const uint4*)(src + (size_t)pl * 64 + ch);
            }
            __syncthreads();

#pragma unroll
            for (int kx = 0; kx < 5; kx++) {
                const int t = ky * 5 + kx;
                const ushort* bbase = &XROW[(ptile * 32 + n + kx) * SP + h * 8];
#pragma unroll
                for (int c2 = 0; c2 < 2; c2++) {
                    const int cs = tset * 2 + c2;
                    bf16x8 af = *(const bf16x8*)(WAf + (((size_t)t * 4 + cs) * 64 + lane) * 8);
                    bf16x8 bf = *(const bf16x8*)(bbase + cs * 16);
                    acc = __builtin_amdgcn_mfma_f32_32x32x16_bf16(af, bf, acc, 0, 0, 0);
                }
            }
        }
        __syncthreads();                          // last ds_reads done; XROW -> red
        if (tset == 1) {
#pragma unroll
            for (int r = 0; r < 16; r++)
                red[ptile * 1024 + r * 64 + lane] = acc[r];
        }
        __syncthreads();
        if (tset == 0) {
#pragma unroll
            for (int r = 0; r < 16; r++) {
                int oc = (r & 3) + 8 * (r >> 2) + 4 * h;
                if (oc < OCC) {
                    float v = acc[r] + red[ptile * 1024 + r * 64 + lane] + ob[oc];
                    v = fminf(fmaxf(v, -1.f), 1.f);
                    off_lds[oc * 64 + ptile * 32 + n] = v;
                }
            }
        }
        __syncthreads();                          // off_lds ready; red reads done
    }

    // ================= Phase B: deform sample + einsum ====================
    ushort* S = (ushort*)smem;                    // [64 px][SP]
    const int p   = tid >> 2;                     // gather pixel (4 lanes/pixel)
    const int cs4 = (tid & 3) * 16;               // channel section (shorts)

    const int m0 = ptile * 32;                    // o tile
    const int n0 = tset * 32;                     // px tile

    f32x16 acc = {};
    const ushort* xtb = XT + (size_t)b * XP * XP * 64;

    for (int t = 0; t < 9; t++) {
        float dy = off_lds[(2 * t) * 64 + p];
        float dx = off_lds[(2 * t + 1) * 64 + p];
        float py = (float)(y + t / 3 - 1) + dy;
        float px = (float)(half * 64 + p + t % 3 - 1) + dx;
        float y0f = floorf(py), x0f = floorf(px);
        float fy = py - y0f, fx = px - x0f;
        int iy = (int)y0f + 2, ix = (int)x0f + 2;
        float w00 = (1.f - fy) * (1.f - fx), w01 = (1.f - fy) * fx;
        float w10 = fy * (1.f - fx),         w11 = fy * fx;

        const ushort* c00 = xtb + ((size_t)iy * XP + ix) * 64 + cs4;
        const ushort* c10 = c00 + XP * 64;

        uint4 q[8];
        q[0] = *(const uint4*)(c00);      q[1] = *(const uint4*)(c00 + 8);
        q[2] = *(const uint4*)(c00 + 64); q[3] = *(const uint4*)(c00 + 72);
        q[4] = *(const uint4*)(c10);      q[5] = *(const uint4*)(c10 + 8);
        q[6] = *(const uint4*)(c10 + 64); q[7] = *(const uint4*)(c10 + 72);

        __syncthreads();   // S (or red at t=0) reads done before overwrite

#pragma unroll
        for (int m = 0; m < 2; m++) {
            unsigned o4[4];
#pragma unroll
            for (int j = 0; j < 4; j++) {
                unsigned u00 = ((const unsigned*)&q[m])[j];
                unsigned u01 = ((const unsigned*)&q[2 + m])[j];
                unsigned u10 = ((const unsigned*)&q[4 + m])[j];
                unsigned u11 = ((const unsigned*)&q[6 + m])[j];
                float lo = w00 * bfu(u00 << 16) + w01 * bfu(u01 << 16)
                         + w10 * bfu(u10 << 16) + w11 * bfu(u11 << 16);
                float hi = w00 * bfu(u00 & 0xffff0000u) + w01 * bfu(u01 & 0xffff0000u)
                         + w10 * bfu(u10 & 0xffff0000u) + w11 * bfu(u11 & 0xffff0000u);
                o4[j] = (unsigned)f2bf(lo) | ((unsigned)f2bf(hi) << 16);
            }
            *(uint4*)&S[p * SP + cs4 + m * 8] = *(uint4*)o4;
        }
        __syncthreads();

        const ushort* bp = &S[(n0 + n) * SP + h * 8];
#pragma unroll
        for (int cs = 0; cs < 4; cs++) {
            bf16x8 af = *(const bf16x8*)(WDf + ((((size_t)t * 2 + ptile) * 4 + cs) * 64 + lane) * 8);
            bf16x8 bf = *(const bf16x8*)(bp + cs * 16);
            acc = __builtin_amdgcn_mfma_f32_32x32x16_bf16(af, bf, acc, 0, 0, 0);
        }
    }

    // epilogue: C/D col=lane&31 (px), row=(r&3)+8*(r>>2)+4*h (o)
#pragma unroll
    for (int r = 0; r < 16; r++) {
        int o = m0 + (r & 3) + 8 * (r >> 2) + 4 * h;
        out[((size_t)(b * CC + o) * HH + y) * WW + half * 64 + n0 + n] = acc[r];
    }
}

// ---------------------------------------------------------------------------
extern "C" void kernel_launch(void* const* d_in, const int* in_sizes, int n_in,
                              void* d_out, int out_size, void* d_ws, size_t ws_size,
                              hipStream_t stream)
{
    const float* x  = (const float*)d_in[0];   // (8,64,128,128)
    const float* w  = (const float*)d_in[1];   // (64,64,3,3)
    const float* ow = (const float*)d_in[2];   // (18,64,5,5)
    const float* ob = (const float*)d_in[3];   // (18,)
    float* out = (float*)d_out;                // (8,64,128,128)

    // workspace: XT 18,113,536 | WAf 102,400 | WDf 73,728
    ushort* XT  = (ushort*)d_ws;
    ushort* WAf = (ushort*)((char*)d_ws + 18113536);
    ushort* WDf = (ushort*)((char*)d_ws + 18215936);

    prep_kernel<<<2 * BB * HH + 344, 256, 0, stream>>>(x, w, ow, XT, WAf, WDf);
    fused_kernel<<<2 * BB * HH, 256, 0, stream>>>(XT, WAf, WDf, ob, out);
}